// Round 2
// baseline (1038.500 us; speedup 1.0000x reference)
//
#include <hip/hip_runtime.h>

#define IN1 64
#define MID 128
#define OUT2 8

__device__ __forceinline__ void atomAddF(float* p, float v) {
    unsafeAtomicAdd(p, v);  // hw global_atomic_add_f32 (no CAS loop)
}

__global__ void k_init_deg(float* __restrict__ deg, int n) {
    int i = blockIdx.x * blockDim.x + threadIdx.x;
    if (i < n) deg[i] = 1.0f;  // self-loop
}

__global__ void k_count_deg(const int* __restrict__ dst, float* __restrict__ deg, int E) {
    int e = blockIdx.x * blockDim.x + threadIdx.x;
    if (e < E) atomAddF(&deg[dst[e]], 1.0f);
}

__global__ void k_rsqrt_deg(float* __restrict__ deg, int n) {
    int i = blockIdx.x * blockDim.x + threadIdx.x;
    if (i < n) deg[i] = rsqrtf(deg[i]);  // deg >= 1 always
}

// agg[i,:] = x[i,:] * dinv[i]   (self-loop term; scatter adds neighbors on top)
__global__ void k_agginit(const float* __restrict__ x, const float* __restrict__ dinv,
                          float* __restrict__ agg, int n) {
    int gid = blockIdx.x * blockDim.x + threadIdx.x;  // one float4 per thread
    if (gid >= n * (IN1 / 4)) return;
    int row = gid >> 4;
    float di = dinv[row];
    float4 v = ((const float4*)x)[gid];
    v.x *= di; v.y *= di; v.z *= di; v.w *= di;
    ((float4*)agg)[gid] = v;
}

// agg[dst,:] += x[src,:] * dinv[src]; 16 threads per edge, one float4 each
__global__ void k_scatter1(const int* __restrict__ src, const int* __restrict__ dst,
                           const float* __restrict__ x, const float* __restrict__ dinv,
                           float* __restrict__ agg, int E) {
    int gid = blockIdx.x * blockDim.x + threadIdx.x;
    if (gid >= E * 16) return;
    int e = gid >> 4;
    int q = (gid & 15) << 2;  // feat offset 0,4,...,60
    int s = src[e], d = dst[e];
    float di = dinv[s];
    float4 v = *(const float4*)(x + (size_t)s * IN1 + q);
    float* o = agg + (size_t)d * IN1 + q;
    atomAddF(o + 0, v.x * di);
    atomAddF(o + 1, v.y * di);
    atomAddF(o + 2, v.z * di);
    atomAddF(o + 3, v.w * di);
}

// Per row: t = agg[row]*dinv[row]; y = relu(t@W1 + b1); z = dinv[row]*(y@W2)
// z is both stored (scatter source) and written to out (self-loop init).
// 256 threads = 2 rows x 128; no early return before syncs.
__global__ __launch_bounds__(256) void k_fused(const float* __restrict__ agg,
                                               const float* __restrict__ dinv,
                                               const float* __restrict__ W1,
                                               const float* __restrict__ b1,
                                               const float* __restrict__ W2,
                                               float* __restrict__ z,
                                               float* __restrict__ out, int n) {
    __shared__ float t[2][IN1];
    __shared__ float y[2][MID];
    int half = threadIdx.x >> 7;   // row within pair
    int f = threadIdx.x & (MID - 1);
    int row = blockIdx.x * 2 + half;
    bool valid = row < n;
    float di = valid ? dinv[row] : 0.0f;
    if (valid && f < IN1) t[half][f] = agg[(size_t)row * IN1 + f] * di;
    __syncthreads();
    float s1 = 0.0f;
    if (valid) {
        s1 = b1[f];
#pragma unroll
        for (int k = 0; k < IN1; ++k) s1 = fmaf(t[half][k], W1[k * MID + f], s1);
    }
    y[half][f] = s1 > 0.0f ? s1 : 0.0f;
    __syncthreads();
    if (valid && f < OUT2) {
        float s2 = 0.0f;
#pragma unroll
        for (int k = 0; k < MID; ++k) s2 = fmaf(y[half][k], W2[k * OUT2 + f], s2);
        float v = s2 * di;
        z[(size_t)row * OUT2 + f] = v;
        out[(size_t)row * OUT2 + f] = v;
    }
}

// out[dst,:] += z[src,:]; 2 threads per edge, one float4 each
__global__ void k_scatter2(const int* __restrict__ src, const int* __restrict__ dst,
                           const float* __restrict__ z, float* __restrict__ out, int E) {
    int gid = blockIdx.x * blockDim.x + threadIdx.x;
    if (gid >= E * 2) return;
    int e = gid >> 1;
    int q = (gid & 1) << 2;
    int s = src[e], d = dst[e];
    float4 v = *(const float4*)(z + (size_t)s * OUT2 + q);
    float* o = out + (size_t)d * OUT2 + q;
    atomAddF(o + 0, v.x);
    atomAddF(o + 1, v.y);
    atomAddF(o + 2, v.z);
    atomAddF(o + 3, v.w);
}

__global__ void k_final(float* __restrict__ out, const float* __restrict__ dinv,
                        const float* __restrict__ b2, int n) {
    int gid = blockIdx.x * blockDim.x + threadIdx.x;
    if (gid >= n * OUT2) return;
    int row = gid >> 3, c = gid & 7;
    out[gid] = fmaf(out[gid], dinv[row], b2[c]);
}

extern "C" void kernel_launch(void* const* d_in, const int* in_sizes, int n_in,
                              void* d_out, int out_size, void* d_ws, size_t ws_size,
                              hipStream_t stream) {
    const float* x  = (const float*)d_in[0];
    const int*   ei = (const int*)d_in[1];
    const float* W1 = (const float*)d_in[2];
    const float* b1 = (const float*)d_in[3];
    const float* W2 = (const float*)d_in[4];
    const float* b2 = (const float*)d_in[5];
    float* out = (float*)d_out;

    int N = in_sizes[0] / IN1;   // 50000
    int E = in_sizes[1] / 2;     // 800000
    const int* src = ei;
    const int* dst = ei + E;

    // workspace: deg(N) | agg(N*64) | z(N*8)  = 4*N*73 = 14.6 MB
    float* deg = (float*)d_ws;
    float* agg = deg + N;
    float* z   = agg + (size_t)N * IN1;

    const int B = 256;
    k_init_deg<<<(N + B - 1) / B, B, 0, stream>>>(deg, N);
    k_count_deg<<<(E + B - 1) / B, B, 0, stream>>>(dst, deg, E);
    k_rsqrt_deg<<<(N + B - 1) / B, B, 0, stream>>>(deg, N);

    k_agginit<<<((size_t)N * (IN1 / 4) + B - 1) / B, B, 0, stream>>>(x, deg, agg, N);
    k_scatter1<<<((size_t)E * 16 + B - 1) / B, B, 0, stream>>>(src, dst, x, deg, agg, E);

    k_fused<<<(N + 1) / 2, 256, 0, stream>>>(agg, deg, W1, b1, W2, z, out, N);

    k_scatter2<<<((size_t)E * 2 + B - 1) / B, B, 0, stream>>>(src, dst, z, out, E);
    k_final<<<((size_t)N * OUT2 + B - 1) / B, B, 0, stream>>>(out, deg, b2, N);
}

// Round 3
// 346.727 us; speedup vs baseline: 2.9952x; 2.9952x over previous
//
#include <hip/hip_runtime.h>

#define IN1 64
#define MID 128
#define OUT2 8

// ---------- CSR build ----------

__global__ void k_zero(int* __restrict__ deg_i, int n) {
    int i = blockIdx.x * blockDim.x + threadIdx.x;
    if (i < n) deg_i[i] = 0;
}

__global__ void k_count(const int* __restrict__ dst, int* __restrict__ deg_i, int E) {
    int e = blockIdx.x * blockDim.x + threadIdx.x;
    if (e < E) atomicAdd(&deg_i[dst[e]], 1);
}

// Single-workgroup exclusive scan of deg_i -> cursor; also dinv = rsqrt(deg+1).
__global__ __launch_bounds__(1024) void k_scan(const int* __restrict__ deg_i,
                                               int* __restrict__ cursor,
                                               float* __restrict__ dinv, int n) {
    __shared__ int wsum[16];
    __shared__ int carry_s;
    int t = threadIdx.x;
    int lane = t & 63, wid = t >> 6;
    if (t == 0) carry_s = 0;
    __syncthreads();
    for (int base = 0; base < n; base += 1024) {
        int i = base + t;
        int v = (i < n) ? deg_i[i] : 0;
        int s = v;
#pragma unroll
        for (int off = 1; off < 64; off <<= 1) {
            int u = __shfl_up(s, off);
            if (lane >= off) s += u;
        }
        if (lane == 63) wsum[wid] = s;
        __syncthreads();
        if (wid == 0) {
            int w = (lane < 16) ? wsum[lane] : 0;
#pragma unroll
            for (int off = 1; off < 16; off <<= 1) {
                int u = __shfl_up(w, off);
                if (lane >= off) w += u;
            }
            if (lane < 16) wsum[lane] = w;
        }
        __syncthreads();
        int wbase = (wid > 0) ? wsum[wid - 1] : 0;
        int incl = s + wbase + carry_s;
        if (i < n) {
            cursor[i] = incl - v;  // exclusive prefix
            dinv[i] = rsqrtf((float)(v + 1));
        }
        __syncthreads();                 // everyone done reading carry_s
        if (t == 1023) carry_s = incl;   // chunk total + old carry
        __syncthreads();
    }
}

// col[p] = src, p from per-dst cursor. After this, cursor[d] = row end,
// row start = cursor[d] - deg_i[d].
__global__ void k_fill(const int* __restrict__ src, const int* __restrict__ dst,
                       int* __restrict__ cursor, int* __restrict__ col, int E) {
    int e = blockIdx.x * blockDim.x + threadIdx.x;
    if (e < E) {
        int p = atomicAdd(&cursor[dst[e]], 1);
        col[p] = src[e];
    }
}

// ---------- fused layer1 gather + MLP (64 -> 128 -> 8) ----------
// Per node d:
//   t = dinv[d] * ( x[d]*dinv[d] + sum_{s in N(d)} x[s]*dinv[s] )   [64]
//   y = relu(t @ W1 + b1)                                            [128]
//   z[d] = dinv[d] * (y @ W2)                                        [8]
// Block = 256 threads = 2 nodes x 128 lanes.
__global__ __launch_bounds__(256) void k_node(const float* __restrict__ x,
                                              const int* __restrict__ deg_i,
                                              const int* __restrict__ cursor,
                                              const int* __restrict__ col,
                                              const float* __restrict__ dinv,
                                              const float* __restrict__ W1,
                                              const float* __restrict__ b1,
                                              const float* __restrict__ W2,
                                              float* __restrict__ z, int n) {
    __shared__ float ts[2][2][IN1];   // parity partial sums
    __shared__ float t[2][IN1];
    __shared__ float y[2][MID];
    __shared__ float part[2][16][OUT2];

    int half = threadIdx.x >> 7;      // node within pair
    int f = threadIdx.x & (MID - 1);  // 0..127
    int row = blockIdx.x * 2 + half;
    bool valid = row < n;

    float di = valid ? dinv[row] : 0.0f;

    // --- phase A: gather (both 64-lane parities work) ---
    int par = f >> 6, ff = f & (IN1 - 1);
    float acc = 0.0f;
    if (valid) {
        if (par == 0) acc = x[(size_t)row * IN1 + ff] * di;  // self-loop
        int end = cursor[row];
        int start = end - deg_i[row];
        for (int j = start + par; j < end; j += 2) {
            int s = col[j];
            acc = fmaf(x[(size_t)s * IN1 + ff], dinv[s], acc);
        }
    }
    ts[half][par][ff] = acc;
    __syncthreads();
    if (f < IN1) t[half][f] = (ts[half][0][f] + ts[half][1][f]) * di;
    __syncthreads();

    // --- phase B: y = relu(t @ W1 + b1), one lane per output col ---
    float s1 = b1[f];
#pragma unroll
    for (int k = 0; k < IN1; ++k) s1 = fmaf(t[half][k], W1[k * MID + f], s1);
    y[half][f] = s1 > 0.0f ? s1 : 0.0f;
    __syncthreads();

    // --- phase C: z = dinv * (y @ W2), 16 k-chunks x 8 cols ---
    int c = f & (OUT2 - 1), ch = f >> 3;  // ch in [0,16)
    float p = 0.0f;
#pragma unroll
    for (int kk = 0; kk < 8; ++kk) {
        int k = ch * 8 + kk;
        p = fmaf(y[half][k], W2[k * OUT2 + c], p);
    }
    part[half][ch][c] = p;
    __syncthreads();
    if (valid && f < OUT2) {
        float s2 = 0.0f;
#pragma unroll
        for (int ch2 = 0; ch2 < 16; ++ch2) s2 += part[half][ch2][f];
        z[(size_t)row * OUT2 + f] = s2 * di;
    }
}

// ---------- layer2 gather, fused bias: out[d] = dinv[d]*(z[d] + sum z[s]) + b2 ----------
// Block 256 = 32 nodes x 8 lanes.
__global__ __launch_bounds__(256) void k_gather2(const int* __restrict__ deg_i,
                                                 const int* __restrict__ cursor,
                                                 const int* __restrict__ col,
                                                 const float* __restrict__ z,
                                                 const float* __restrict__ dinv,
                                                 const float* __restrict__ b2,
                                                 float* __restrict__ out, int n) {
    int tid = blockIdx.x * blockDim.x + threadIdx.x;
    int d = tid >> 3, f = tid & (OUT2 - 1);
    if (d >= n) return;
    float acc = z[(size_t)d * OUT2 + f];  // self-loop
    int end = cursor[d];
    int start = end - deg_i[d];
    for (int j = start; j < end; ++j) {
        int s = col[j];
        acc += z[(size_t)s * OUT2 + f];
    }
    out[(size_t)d * OUT2 + f] = fmaf(acc, dinv[d], b2[f]);
}

extern "C" void kernel_launch(void* const* d_in, const int* in_sizes, int n_in,
                              void* d_out, int out_size, void* d_ws, size_t ws_size,
                              hipStream_t stream) {
    const float* x  = (const float*)d_in[0];
    const int*   ei = (const int*)d_in[1];
    const float* W1 = (const float*)d_in[2];
    const float* b1 = (const float*)d_in[3];
    const float* W2 = (const float*)d_in[4];
    const float* b2 = (const float*)d_in[5];
    float* out = (float*)d_out;

    int N = in_sizes[0] / IN1;  // 50000
    int E = in_sizes[1] / 2;    // 800000
    const int* src = ei;
    const int* dst = ei + E;

    // workspace: deg_i(N) | cursor(N) | col(E) | dinv(N) | z(8N)  = 5.4 MB
    int* deg_i  = (int*)d_ws;
    int* cursor = deg_i + N;
    int* col    = cursor + N;
    float* dinv = (float*)(col + E);
    float* z    = dinv + N;

    const int B = 256;
    k_zero<<<(N + B - 1) / B, B, 0, stream>>>(deg_i, N);
    k_count<<<(E + B - 1) / B, B, 0, stream>>>(dst, deg_i, E);
    k_scan<<<1, 1024, 0, stream>>>(deg_i, cursor, dinv, N);
    k_fill<<<(E + B - 1) / B, B, 0, stream>>>(src, dst, cursor, col, E);

    k_node<<<(N + 1) / 2, 256, 0, stream>>>(x, deg_i, cursor, col, dinv, W1, b1, W2, z, N);
    k_gather2<<<((size_t)N * OUT2 + B - 1) / B, B, 0, stream>>>(deg_i, cursor, col, z, dinv, b2, out, N);
}

// Round 4
// 235.672 us; speedup vs baseline: 4.4065x; 1.4712x over previous
//
#include <hip/hip_runtime.h>

#define IN1 64
#define MID 128
#define OUT2 8

// ---------------- CSR build ----------------

__global__ void k_zero(int* __restrict__ deg_i, int n) {
    int i = blockIdx.x * blockDim.x + threadIdx.x;
    if (i < n) deg_i[i] = 0;
}

__global__ void k_count(const int* __restrict__ dst, int* __restrict__ deg_i, int E) {
    int e = blockIdx.x * blockDim.x + threadIdx.x;
    if (e < E) atomicAdd(&deg_i[dst[e]], 1);
}

// per-block sum of deg + dinv = rsqrt(deg+1)
__global__ __launch_bounds__(256) void k_bsum(const int* __restrict__ deg_i,
                                              float* __restrict__ dinv,
                                              int* __restrict__ bsum, int n) {
    __shared__ int wsum[4];
    int t = threadIdx.x, i = blockIdx.x * 256 + t;
    int lane = t & 63, wid = t >> 6;
    int v = (i < n) ? deg_i[i] : 0;
    if (i < n) dinv[i] = rsqrtf((float)(v + 1));
    int s = v;
#pragma unroll
    for (int off = 1; off < 64; off <<= 1) s += __shfl_xor(s, off, 64);
    if (lane == 0) wsum[wid] = s;
    __syncthreads();
    if (t == 0) bsum[blockIdx.x] = wsum[0] + wsum[1] + wsum[2] + wsum[3];
}

// exclusive scan of bsum[G], G <= 256, single block
__global__ __launch_bounds__(256) void k_scanb(int* __restrict__ bsum, int G) {
    __shared__ int ws_[4];
    int t = threadIdx.x, lane = t & 63, wid = t >> 6;
    int v = (t < G) ? bsum[t] : 0;
    int s = v;
#pragma unroll
    for (int off = 1; off < 64; off <<= 1) {
        int u = __shfl_up(s, off, 64);
        if (lane >= off) s += u;
    }
    if (lane == 63) ws_[wid] = s;
    __syncthreads();
    int add = 0;
    for (int w = 0; w < wid; ++w) add += ws_[w];
    if (t < G) bsum[t] = s - v + add;  // exclusive
}

// cursor[i] = global exclusive prefix of deg
__global__ __launch_bounds__(256) void k_rowptr(const int* __restrict__ deg_i,
                                                const int* __restrict__ bsum,
                                                int* __restrict__ cursor, int n) {
    __shared__ int wsum[4];
    int t = threadIdx.x, i = blockIdx.x * 256 + t;
    int lane = t & 63, wid = t >> 6;
    int v = (i < n) ? deg_i[i] : 0;
    int s = v;
#pragma unroll
    for (int off = 1; off < 64; off <<= 1) {
        int u = __shfl_up(s, off, 64);
        if (lane >= off) s += u;
    }
    if (lane == 63) wsum[wid] = s;
    __syncthreads();
    int add = bsum[blockIdx.x];
    for (int w = 0; w < wid; ++w) add += wsum[w];
    if (i < n) cursor[i] = s - v + add;
}

// col[p]=src via cursor atomics; afterwards cursor[d] = row end
__global__ void k_fill(const int* __restrict__ src, const int* __restrict__ dst,
                       int* __restrict__ cursor, int* __restrict__ col, int E) {
    int e = blockIdx.x * blockDim.x + threadIdx.x;
    if (e < E) {
        int p = atomicAdd(&cursor[dst[e]], 1);
        col[p] = src[e];
    }
}

// ---------------- fused layer1: gather + 64->128->8 MLP ----------------
// One wave handles 4 nodes; block = 4 waves = 16 nodes.
__global__ __launch_bounds__(256) void k_node(const float* __restrict__ x,
                                              const int* __restrict__ deg_i,
                                              const int* __restrict__ cursor,
                                              const int* __restrict__ col,
                                              const float* __restrict__ dinv,
                                              const float* __restrict__ W1,
                                              const float* __restrict__ b1,
                                              const float* __restrict__ W2,
                                              float* __restrict__ z, int n) {
    __shared__ float w2t[OUT2 * MID];  // transposed: w2t[c*128+k]
    __shared__ float tS[4][4][IN1];
    __shared__ float yS[4][4][MID];

    int t = threadIdx.x;
    for (int i = t; i < MID * OUT2; i += 256) w2t[(i & 7) * MID + (i >> 3)] = W2[i];

    int lane = t & 63, wave = t >> 6;
    int row0 = blockIdx.x * 16 + wave * 4;

    // phase A: gather 4 nodes, unroll-4 over neighbors (4 x-rows in flight)
#pragma unroll
    for (int nd = 0; nd < 4; ++nd) {
        int row = row0 + nd;
        float acc = 0.0f, di = 0.0f;
        if (row < n) {
            di = dinv[row];
            acc = x[(size_t)row * IN1 + lane] * di;  // self-loop
            int end = cursor[row];
            int j = end - deg_i[row];
            for (; j + 3 < end; j += 4) {
                int s0 = col[j], s1 = col[j + 1], s2 = col[j + 2], s3 = col[j + 3];
                float v0 = x[(size_t)s0 * IN1 + lane];
                float d0 = dinv[s0];
                float v1 = x[(size_t)s1 * IN1 + lane];
                float d1 = dinv[s1];
                float v2 = x[(size_t)s2 * IN1 + lane];
                float d2 = dinv[s2];
                float v3 = x[(size_t)s3 * IN1 + lane];
                float d3 = dinv[s3];
                acc = fmaf(v0, d0, acc);
                acc = fmaf(v1, d1, acc);
                acc = fmaf(v2, d2, acc);
                acc = fmaf(v3, d3, acc);
            }
            for (; j < end; ++j) {
                int s = col[j];
                acc = fmaf(x[(size_t)s * IN1 + lane], dinv[s], acc);
            }
        }
        tS[wave][nd][lane] = acc * di;
    }
    __syncthreads();

    // phase B: y[nd] = relu(t[nd] @ W1 + b1); lane covers cols {lane, lane+64};
    // one W1 read serves 4 nodes (register blocking)
    float ya0 = b1[lane], yb0 = b1[lane + 64];
    float ya1 = ya0, yb1 = yb0, ya2 = ya0, yb2 = yb0, ya3 = ya0, yb3 = yb0;
#pragma unroll 8
    for (int k = 0; k < IN1; ++k) {
        float wa = W1[k * MID + lane];
        float wb = W1[k * MID + lane + 64];
        float t0 = tS[wave][0][k], t1 = tS[wave][1][k];
        float t2 = tS[wave][2][k], t3 = tS[wave][3][k];
        ya0 = fmaf(t0, wa, ya0); yb0 = fmaf(t0, wb, yb0);
        ya1 = fmaf(t1, wa, ya1); yb1 = fmaf(t1, wb, yb1);
        ya2 = fmaf(t2, wa, ya2); yb2 = fmaf(t2, wb, yb2);
        ya3 = fmaf(t3, wa, ya3); yb3 = fmaf(t3, wb, yb3);
    }
    yS[wave][0][lane] = fmaxf(ya0, 0.f); yS[wave][0][lane + 64] = fmaxf(yb0, 0.f);
    yS[wave][1][lane] = fmaxf(ya1, 0.f); yS[wave][1][lane + 64] = fmaxf(yb1, 0.f);
    yS[wave][2][lane] = fmaxf(ya2, 0.f); yS[wave][2][lane + 64] = fmaxf(yb2, 0.f);
    yS[wave][3][lane] = fmaxf(ya3, 0.f); yS[wave][3][lane + 64] = fmaxf(yb3, 0.f);
    __syncthreads();

    // phase C: z[nd] = dinv * (y[nd] @ W2); lane = (nd = lane>>4, ch = lane&15)
    int nd = lane >> 4, ch = lane & 15;
    float p[OUT2];
#pragma unroll
    for (int c = 0; c < OUT2; ++c) p[c] = 0.0f;
#pragma unroll
    for (int kk = 0; kk < 8; ++kk) {
        int k = ch * 8 + kk;
        float yk = yS[wave][nd][k];
#pragma unroll
        for (int c = 0; c < OUT2; ++c) p[c] = fmaf(yk, w2t[c * MID + k], p[c]);
    }
#pragma unroll
    for (int off = 1; off < 16; off <<= 1) {
#pragma unroll
        for (int c = 0; c < OUT2; ++c) p[c] += __shfl_xor(p[c], off, 64);
    }
    int row = row0 + nd;
    int pos = ch;
    if (row < n && pos < OUT2) {
        z[(size_t)row * OUT2 + pos] = p[pos] * dinv[row];
    }
}

// ---------------- layer2 gather: wave per node, 8 nb x 8 feat ----------------
__global__ __launch_bounds__(256) void k_gather2(const int* __restrict__ deg_i,
                                                 const int* __restrict__ cursor,
                                                 const int* __restrict__ col,
                                                 const float* __restrict__ z,
                                                 const float* __restrict__ dinv,
                                                 const float* __restrict__ b2,
                                                 float* __restrict__ out, int n) {
    int t = threadIdx.x, lane = t & 63, wave = t >> 6;
    int node = blockIdx.x * 4 + wave;
    if (node >= n) return;
    int nb = lane >> 3, c = lane & 7;
    float acc = (nb == 0) ? z[(size_t)node * OUT2 + c] : 0.0f;  // self-loop
    int end = cursor[node];
    int start = end - deg_i[node];
    for (int j = start + nb; j < end; j += 8) {
        acc += z[(size_t)col[j] * OUT2 + c];
    }
#pragma unroll
    for (int off = 8; off < 64; off <<= 1) acc += __shfl_xor(acc, off, 64);
    if (lane < OUT2) out[(size_t)node * OUT2 + lane] = fmaf(acc, dinv[node], b2[lane]);
}

extern "C" void kernel_launch(void* const* d_in, const int* in_sizes, int n_in,
                              void* d_out, int out_size, void* d_ws, size_t ws_size,
                              hipStream_t stream) {
    const float* x  = (const float*)d_in[0];
    const int*   ei = (const int*)d_in[1];
    const float* W1 = (const float*)d_in[2];
    const float* b1 = (const float*)d_in[3];
    const float* W2 = (const float*)d_in[4];
    const float* b2 = (const float*)d_in[5];
    float* out = (float*)d_out;

    int N = in_sizes[0] / IN1;  // 50000
    int E = in_sizes[1] / 2;    // 800000
    const int* src = ei;
    const int* dst = ei + E;

    // ws: deg_i(N) | cursor(N) | col(E) | dinv(N) | z(8N) | bsum(256)  ~5.4 MB
    int* deg_i  = (int*)d_ws;
    int* cursor = deg_i + N;
    int* col    = cursor + N;
    float* dinv = (float*)(col + E);
    float* z    = dinv + N;
    int* bsum   = (int*)(z + (size_t)N * OUT2);

    const int B = 256;
    int G = (N + B - 1) / B;  // 196 blocks (<=256 required by k_scanb)

    k_zero<<<G, B, 0, stream>>>(deg_i, N);
    k_count<<<(E + B - 1) / B, B, 0, stream>>>(dst, deg_i, E);
    k_bsum<<<G, B, 0, stream>>>(deg_i, dinv, bsum, N);
    k_scanb<<<1, B, 0, stream>>>(bsum, G);
    k_rowptr<<<G, B, 0, stream>>>(deg_i, bsum, cursor, N);
    k_fill<<<(E + B - 1) / B, B, 0, stream>>>(src, dst, cursor, col, E);

    k_node<<<(N + 15) / 16, 256, 0, stream>>>(x, deg_i, cursor, col, dinv, W1, b1, W2, z, N);
    k_gather2<<<(N + 3) / 4, 256, 0, stream>>>(deg_i, cursor, col, z, dinv, b2, out, N);
}

// Round 5
// 228.221 us; speedup vs baseline: 4.5504x; 1.0326x over previous
//
#include <hip/hip_runtime.h>

#define IN1 64
#define MID 128
#define OUT2 8
#define YPAD 132  // MID+4: breaks phase-C bank alignment

// ---------------- CSR build ----------------

__global__ void k_count(const int* __restrict__ dst, int* __restrict__ deg_i, int E2, int E) {
    int gid = blockIdx.x * blockDim.x + threadIdx.x;
    if (gid < E2) {
        int2 d = ((const int2*)dst)[gid];
        atomicAdd(&deg_i[d.x], 1);
        atomicAdd(&deg_i[d.y], 1);
    }
    if (gid == 0 && (E & 1)) atomicAdd(&deg_i[dst[E - 1]], 1);
}

// per-block sum of deg + dinv = rsqrt(deg+1)
__global__ __launch_bounds__(256) void k_bsum(const int* __restrict__ deg_i,
                                              float* __restrict__ dinv,
                                              int* __restrict__ bsum, int n) {
    __shared__ int wsum[4];
    int t = threadIdx.x, i = blockIdx.x * 256 + t;
    int lane = t & 63, wid = t >> 6;
    int v = (i < n) ? deg_i[i] : 0;
    if (i < n) dinv[i] = rsqrtf((float)(v + 1));
    int s = v;
#pragma unroll
    for (int off = 1; off < 64; off <<= 1) s += __shfl_xor(s, off, 64);
    if (lane == 0) wsum[wid] = s;
    __syncthreads();
    if (t == 0) bsum[blockIdx.x] = wsum[0] + wsum[1] + wsum[2] + wsum[3];
}

// exclusive scan of bsum[G], G <= 256, single block
__global__ __launch_bounds__(256) void k_scanb(int* __restrict__ bsum, int G) {
    __shared__ int ws_[4];
    int t = threadIdx.x, lane = t & 63, wid = t >> 6;
    int v = (t < G) ? bsum[t] : 0;
    int s = v;
#pragma unroll
    for (int off = 1; off < 64; off <<= 1) {
        int u = __shfl_up(s, off, 64);
        if (lane >= off) s += u;
    }
    if (lane == 63) ws_[wid] = s;
    __syncthreads();
    int add = 0;
    for (int w = 0; w < wid; ++w) add += ws_[w];
    if (t < G) bsum[t] = s - v + add;  // exclusive
}

// cursor[i] = global exclusive prefix of deg
__global__ __launch_bounds__(256) void k_rowptr(const int* __restrict__ deg_i,
                                                const int* __restrict__ bsum,
                                                int* __restrict__ cursor, int n) {
    __shared__ int wsum[4];
    int t = threadIdx.x, i = blockIdx.x * 256 + t;
    int lane = t & 63, wid = t >> 6;
    int v = (i < n) ? deg_i[i] : 0;
    int s = v;
#pragma unroll
    for (int off = 1; off < 64; off <<= 1) {
        int u = __shfl_up(s, off, 64);
        if (lane >= off) s += u;
    }
    if (lane == 63) wsum[wid] = s;
    __syncthreads();
    int add = bsum[blockIdx.x];
    for (int w = 0; w < wid; ++w) add += wsum[w];
    if (i < n) cursor[i] = s - v + add;
}

// col[p]=src via cursor atomics; afterwards cursor[d] = row end
__global__ void k_fill(const int* __restrict__ src, const int* __restrict__ dst,
                       int* __restrict__ cursor, int* __restrict__ col, int E2, int E) {
    int gid = blockIdx.x * blockDim.x + threadIdx.x;
    if (gid < E2) {
        int2 s = ((const int2*)src)[gid];
        int2 d = ((const int2*)dst)[gid];
        int p0 = atomicAdd(&cursor[d.x], 1);
        col[p0] = s.x;
        int p1 = atomicAdd(&cursor[d.y], 1);
        col[p1] = s.y;
    }
    if (gid == 0 && (E & 1)) {
        int p = atomicAdd(&cursor[dst[E - 1]], 1);
        col[p] = src[E - 1];
    }
}

// ---------------- fused layer1: gather + 64->128->8 MLP ----------------
// One wave handles 4 nodes; block = 4 waves = 16 nodes.
__global__ __launch_bounds__(256) void k_node(const float* __restrict__ x,
                                              const int* __restrict__ deg_i,
                                              const int* __restrict__ cursor,
                                              const int* __restrict__ col,
                                              const float* __restrict__ dinv,
                                              const float* __restrict__ W1,
                                              const float* __restrict__ b1,
                                              const float* __restrict__ W2,
                                              float* __restrict__ z, int n) {
    __shared__ float w2s[MID * OUT2];   // original layout [k][c]
    __shared__ float tS[4][4][IN1];
    __shared__ float yS[4][4][YPAD];

    int t = threadIdx.x;
    // cooperative W2 load: 256 threads x float4 = 1024 floats exactly
    ((float4*)w2s)[t] = ((const float4*)W2)[t];

    int lane = t & 63, wave = t >> 6;
    int row0 = blockIdx.x * 16 + wave * 4;

    // phase A: gather 4 nodes, unroll-8 (16 loads in flight), dual accumulators
#pragma unroll
    for (int nd = 0; nd < 4; ++nd) {
        int row = row0 + nd;
        float acc0 = 0.0f, acc1 = 0.0f, di = 0.0f;
        if (row < n) {
            di = dinv[row];
            acc0 = x[(size_t)row * IN1 + lane] * di;  // self-loop
            int end = cursor[row];
            int j = end - deg_i[row];
            for (; j + 7 < end; j += 8) {
                int s0 = col[j], s1 = col[j + 1], s2 = col[j + 2], s3 = col[j + 3];
                int s4 = col[j + 4], s5 = col[j + 5], s6 = col[j + 6], s7 = col[j + 7];
                float v0 = x[(size_t)s0 * IN1 + lane], d0 = dinv[s0];
                float v1 = x[(size_t)s1 * IN1 + lane], d1 = dinv[s1];
                float v2 = x[(size_t)s2 * IN1 + lane], d2 = dinv[s2];
                float v3 = x[(size_t)s3 * IN1 + lane], d3 = dinv[s3];
                float v4 = x[(size_t)s4 * IN1 + lane], d4 = dinv[s4];
                float v5 = x[(size_t)s5 * IN1 + lane], d5 = dinv[s5];
                float v6 = x[(size_t)s6 * IN1 + lane], d6 = dinv[s6];
                float v7 = x[(size_t)s7 * IN1 + lane], d7 = dinv[s7];
                acc0 = fmaf(v0, d0, acc0); acc1 = fmaf(v1, d1, acc1);
                acc0 = fmaf(v2, d2, acc0); acc1 = fmaf(v3, d3, acc1);
                acc0 = fmaf(v4, d4, acc0); acc1 = fmaf(v5, d5, acc1);
                acc0 = fmaf(v6, d6, acc0); acc1 = fmaf(v7, d7, acc1);
            }
            for (; j < end; ++j) {
                int s = col[j];
                acc0 = fmaf(x[(size_t)s * IN1 + lane], dinv[s], acc0);
            }
        }
        tS[wave][nd][lane] = (acc0 + acc1) * di;
    }
    __syncthreads();

    // phase B: y = relu(t @ W1 + b1); lane covers cols {lane, lane+64};
    // float4 LDS broadcast reads, one W1 read serves 4 nodes
    float ya0 = b1[lane], yb0 = b1[lane + 64];
    float ya1 = ya0, yb1 = yb0, ya2 = ya0, yb2 = yb0, ya3 = ya0, yb3 = yb0;
#pragma unroll 4
    for (int k4 = 0; k4 < IN1; k4 += 4) {
        float4 t0 = *(const float4*)&tS[wave][0][k4];
        float4 t1 = *(const float4*)&tS[wave][1][k4];
        float4 t2 = *(const float4*)&tS[wave][2][k4];
        float4 t3 = *(const float4*)&tS[wave][3][k4];
#pragma unroll
        for (int kk = 0; kk < 4; ++kk) {
            int k = k4 + kk;
            float wa = W1[k * MID + lane];
            float wb = W1[k * MID + lane + 64];
            float e0 = (&t0.x)[kk], e1 = (&t1.x)[kk], e2 = (&t2.x)[kk], e3 = (&t3.x)[kk];
            ya0 = fmaf(e0, wa, ya0); yb0 = fmaf(e0, wb, yb0);
            ya1 = fmaf(e1, wa, ya1); yb1 = fmaf(e1, wb, yb1);
            ya2 = fmaf(e2, wa, ya2); yb2 = fmaf(e2, wb, yb2);
            ya3 = fmaf(e3, wa, ya3); yb3 = fmaf(e3, wb, yb3);
        }
    }
    yS[wave][0][lane] = fmaxf(ya0, 0.f); yS[wave][0][lane + 64] = fmaxf(yb0, 0.f);
    yS[wave][1][lane] = fmaxf(ya1, 0.f); yS[wave][1][lane + 64] = fmaxf(yb1, 0.f);
    yS[wave][2][lane] = fmaxf(ya2, 0.f); yS[wave][2][lane + 64] = fmaxf(yb2, 0.f);
    yS[wave][3][lane] = fmaxf(ya3, 0.f); yS[wave][3][lane + 64] = fmaxf(yb3, 0.f);
    __syncthreads();

    // phase C: z = dinv * (y @ W2); lane=(nd,ch), k = kk*16+ch (conflict-light)
    int nd = lane >> 4, ch = lane & 15;
    float p[OUT2];
#pragma unroll
    for (int c = 0; c < OUT2; ++c) p[c] = 0.0f;
#pragma unroll
    for (int kk = 0; kk < 8; ++kk) {
        int k = kk * 16 + ch;
        float yk = yS[wave][nd][k];
        float4 wlo = *(const float4*)&w2s[k * OUT2];
        float4 whi = *(const float4*)&w2s[k * OUT2 + 4];
        p[0] = fmaf(yk, wlo.x, p[0]); p[1] = fmaf(yk, wlo.y, p[1]);
        p[2] = fmaf(yk, wlo.z, p[2]); p[3] = fmaf(yk, wlo.w, p[3]);
        p[4] = fmaf(yk, whi.x, p[4]); p[5] = fmaf(yk, whi.y, p[5]);
        p[6] = fmaf(yk, whi.z, p[6]); p[7] = fmaf(yk, whi.w, p[7]);
    }
#pragma unroll
    for (int off = 1; off < 16; off <<= 1) {
#pragma unroll
        for (int c = 0; c < OUT2; ++c) p[c] += __shfl_xor(p[c], off, 64);
    }
    int row = row0 + nd;
    if (row < n && ch < OUT2) {
        z[(size_t)row * OUT2 + ch] = p[ch] * dinv[row];
    }
}

// ---------------- layer2 gather: wave per node, 8 nb x 8 feat, unroll 2 ----------------
__global__ __launch_bounds__(256) void k_gather2(const int* __restrict__ deg_i,
                                                 const int* __restrict__ cursor,
                                                 const int* __restrict__ col,
                                                 const float* __restrict__ z,
                                                 const float* __restrict__ dinv,
                                                 const float* __restrict__ b2,
                                                 float* __restrict__ out, int n) {
    int t = threadIdx.x, lane = t & 63, wave = t >> 6;
    int node = blockIdx.x * 4 + wave;
    if (node >= n) return;
    int nb = lane >> 3, c = lane & 7;
    float acc = (nb == 0) ? z[(size_t)node * OUT2 + c] : 0.0f;  // self-loop
    int end = cursor[node];
    int j = end - deg_i[node] + nb;
    for (; j + 8 < end; j += 16) {
        int s0 = col[j], s1 = col[j + 8];
        float a0 = z[(size_t)s0 * OUT2 + c];
        float a1 = z[(size_t)s1 * OUT2 + c];
        acc += a0 + a1;
    }
    if (j < end) acc += z[(size_t)col[j] * OUT2 + c];
#pragma unroll
    for (int off = 8; off < 64; off <<= 1) acc += __shfl_xor(acc, off, 64);
    if (lane < OUT2) out[(size_t)node * OUT2 + lane] = fmaf(acc, dinv[node], b2[lane]);
}

extern "C" void kernel_launch(void* const* d_in, const int* in_sizes, int n_in,
                              void* d_out, int out_size, void* d_ws, size_t ws_size,
                              hipStream_t stream) {
    const float* x  = (const float*)d_in[0];
    const int*   ei = (const int*)d_in[1];
    const float* W1 = (const float*)d_in[2];
    const float* b1 = (const float*)d_in[3];
    const float* W2 = (const float*)d_in[4];
    const float* b2 = (const float*)d_in[5];
    float* out = (float*)d_out;

    int N = in_sizes[0] / IN1;  // 50000
    int E = in_sizes[1] / 2;    // 800000
    const int* src = ei;
    const int* dst = ei + E;

    // ws: deg_i(N) | cursor(N) | col(E) | dinv(N) | z(8N) | bsum(256)  ~5.4 MB
    int* deg_i  = (int*)d_ws;
    int* cursor = deg_i + N;
    int* col    = cursor + N;
    float* dinv = (float*)(col + E);
    float* z    = dinv + N;
    int* bsum   = (int*)(z + (size_t)N * OUT2);

    const int B = 256;
    int G = (N + B - 1) / B;  // 196 (<=256 required by k_scanb)
    int E2 = E / 2;

    hipMemsetAsync(deg_i, 0, (size_t)N * sizeof(int), stream);
    k_count<<<(E2 + B - 1) / B, B, 0, stream>>>(dst, deg_i, E2, E);
    k_bsum<<<G, B, 0, stream>>>(deg_i, dinv, bsum, N);
    k_scanb<<<1, B, 0, stream>>>(bsum, G);
    k_rowptr<<<G, B, 0, stream>>>(deg_i, bsum, cursor, N);
    k_fill<<<(E2 + B - 1) / B, B, 0, stream>>>(src, dst, cursor, col, E2, E);

    k_node<<<(N + 15) / 16, 256, 0, stream>>>(x, deg_i, cursor, col, dinv, W1, b1, W2, z, N);
    k_gather2<<<(N + 3) / 4, 256, 0, stream>>>(deg_i, cursor, col, z, dinv, b2, out, N);
}